// Round 4
// baseline (826.033 us; speedup 1.0000x reference)
//
#include <hip/hip_runtime.h>
#include <hip/hip_bf16.h>
#include <math.h>

// MoE: T=8192 tokens, D=1024, E=8 experts, F=4096, top-2 routing.
// Pipeline: cast -> router -> count -> scan(+tile maps) -> scatter
//           -> transpose(w1) -> GEMM1(gelu)->H -> transpose(w2) -> GEMM2 -> atomic scatter-add.
// GEMM: 256x256 tile, BK=32, 8 waves, 4-deep LDS ring (128 KB), 2 phases/K-tile,
// mfma_f32_32x32x16_bf16 (half the LDS reads + MFMA instrs of 16x16x32),
// counted vmcnt(8) (2-K-tile cover), setprio around MFMA clusters, NO sched_barrier
// pinning / NO manual lgkm drains (compiler emits counted lgkmcnt; vmcnt asm's
// "memory" clobber fences LDS reads across K-tile boundaries).
// 128B-line XOR-swizzled LDS, global_load_lds staging (pre-swizzled per-lane
// global source, linear LDS dest).

#define TK 8192
#define DDIM 1024
#define FDIM 4096
#define NEXP 8
#define MAXT256 72
#define MAXT128 136

typedef unsigned short u16;
typedef __attribute__((ext_vector_type(8))) short bf16x8;
typedef __attribute__((ext_vector_type(4))) float f32x4;
typedef __attribute__((ext_vector_type(16))) float f32x16;

typedef const __attribute__((address_space(1))) unsigned int* gp_u32;
typedef __attribute__((address_space(3))) unsigned int* lp_u32;

__device__ __forceinline__ u16 f2bf(float f) {
  unsigned x = __float_as_uint(f);
  x += 0x7fffu + ((x >> 16) & 1u);
  return (u16)(x >> 16);
}

// ---------------- cast x (fp32 -> bf16), 8 elems/thread ----------------
__global__ void cast_x_kernel(const float4* __restrict__ x, uint4* __restrict__ xb) {
  int i = blockIdx.x * blockDim.x + threadIdx.x;
  float4 a = x[2 * i], b = x[2 * i + 1];
  uint4 o;
  o.x = (unsigned)f2bf(a.x) | ((unsigned)f2bf(a.y) << 16);
  o.y = (unsigned)f2bf(a.z) | ((unsigned)f2bf(a.w) << 16);
  o.z = (unsigned)f2bf(b.x) | ((unsigned)f2bf(b.y) << 16);
  o.w = (unsigned)f2bf(b.z) | ((unsigned)f2bf(b.w) << 16);
  xb[i] = o;
}

// ---------------- weight transpose + cast: [E][K][N] f32 -> [E][N][K] bf16 ----------------
__global__ void transpose_cast_kernel(const float* __restrict__ src, u16* __restrict__ dst,
                                      int K, int N) {
  __shared__ float tile[64][65];
  const int t = threadIdx.x;
  const float* s = src + (size_t)blockIdx.z * K * N + (size_t)(blockIdx.x * 64) * N + blockIdx.y * 64;
  u16* d = dst + (size_t)blockIdx.z * N * K + (size_t)(blockIdx.y * 64) * K + blockIdx.x * 64;
#pragma unroll
  for (int r = 0; r < 16; ++r) {
    int idx = r * 256 + t;
    int kk = idx >> 6, nn = idx & 63;
    tile[kk][nn] = s[(size_t)kk * N + nn];
  }
  __syncthreads();
#pragma unroll
  for (int r = 0; r < 16; ++r) {
    int idx = r * 256 + t;
    int nn = idx >> 6, kk = idx & 63;
    d[(size_t)nn * K + kk] = f2bf(tile[kk][nn]);
  }
}

// ---------------- router: one wave per token ----------------
__global__ void router_kernel(const float* __restrict__ x, const float* __restrict__ gw,
                              const float* __restrict__ gb,
                              int* __restrict__ top_e, float* __restrict__ top_w) {
  const int t = blockIdx.x;
  const int l = threadIdx.x;  // 64
  const float* xr = x + (size_t)t * DDIM;
  float acc[8] = {0, 0, 0, 0, 0, 0, 0, 0};
  for (int k = l; k < DDIM; k += 64) {
    float xv = xr[k];
    const float4* g4 = (const float4*)(gw + (size_t)k * 8);
    float4 ga = g4[0], gbv = g4[1];
    acc[0] = fmaf(xv, ga.x, acc[0]);  acc[1] = fmaf(xv, ga.y, acc[1]);
    acc[2] = fmaf(xv, ga.z, acc[2]);  acc[3] = fmaf(xv, ga.w, acc[3]);
    acc[4] = fmaf(xv, gbv.x, acc[4]); acc[5] = fmaf(xv, gbv.y, acc[5]);
    acc[6] = fmaf(xv, gbv.z, acc[6]); acc[7] = fmaf(xv, gbv.w, acc[7]);
  }
#pragma unroll
  for (int e = 0; e < 8; ++e)
#pragma unroll
    for (int m = 32; m; m >>= 1) acc[e] += __shfl_xor(acc[e], m, 64);
  if (l == 0) {
    float lg[8];
#pragma unroll
    for (int e = 0; e < 8; ++e) lg[e] = acc[e] + gb[e];
    int i1 = 0;
#pragma unroll
    for (int e = 1; e < 8; ++e) if (lg[e] > lg[i1]) i1 = e;
    int i2 = (i1 == 0) ? 1 : 0;
#pragma unroll
    for (int e = 0; e < 8; ++e) if (e != i1 && lg[e] > lg[i2]) i2 = e;
    float e2 = __expf(lg[i2] - lg[i1]);
    float inv = 1.0f / (1.0f + e2);
    top_e[2 * t] = i1;      top_e[2 * t + 1] = i2;
    top_w[2 * t] = inv;     top_w[2 * t + 1] = e2 * inv;
  }
}

// ---------------- count ----------------
__global__ void count_kernel(const int* __restrict__ top_e, int* __restrict__ counts) {
  __shared__ int lc[8];
  if (threadIdx.x < 8) lc[threadIdx.x] = 0;
  __syncthreads();
  int t = blockIdx.x * 256 + threadIdx.x;
  if (t < TK) {
    atomicAdd(&lc[top_e[2 * t]], 1);
    atomicAdd(&lc[top_e[2 * t + 1]], 1);
  }
  __syncthreads();
  if (threadIdx.x < 8) atomicAdd(&counts[threadIdx.x], lc[threadIdx.x]);
}

// ---------------- scan + tile maps ----------------
__global__ void scan_kernel(const int* __restrict__ counts, int* __restrict__ seg,
                            int* __restrict__ cur, int* __restrict__ nt256,
                            int* __restrict__ map256, int* __restrict__ nt128,
                            int* __restrict__ map128) {
  if (threadIdx.x == 0) {
    int s = 0, i256 = 0, i128 = 0;
    for (int e = 0; e < 8; ++e) {
      seg[e] = s; cur[e] = s;
      int c = counts[e];
      for (int mt = 0; mt * 256 < c; ++mt) map256[i256++] = (e << 16) | mt;
      for (int mt = 0; mt * 128 < c; ++mt) map128[i128++] = (e << 16) | mt;
      s += c;
    }
    seg[8] = s;
    *nt256 = i256;
    *nt128 = i128;
  }
}

// ---------------- scatter ----------------
__global__ void scatter_kernel(const int* __restrict__ top_e, const float* __restrict__ top_w,
                               int* __restrict__ cur, int* __restrict__ tok_ids,
                               float* __restrict__ tok_wt) {
  __shared__ int lcnt[8];
  __shared__ int lbase[8];
  if (threadIdx.x < 8) lcnt[threadIdx.x] = 0;
  __syncthreads();
  int t = blockIdx.x * 256 + threadIdx.x;
  int e[2]; float wv[2]; int lpos[2];
  bool valid = t < TK;
  if (valid) {
#pragma unroll
    for (int j = 0; j < 2; ++j) {
      e[j] = top_e[2 * t + j];
      wv[j] = top_w[2 * t + j];
      lpos[j] = atomicAdd(&lcnt[e[j]], 1);
    }
  }
  __syncthreads();
  if (threadIdx.x < 8) lbase[threadIdx.x] = atomicAdd(&cur[threadIdx.x], lcnt[threadIdx.x]);
  __syncthreads();
  if (valid) {
#pragma unroll
    for (int j = 0; j < 2; ++j) {
      int slot = lbase[e[j]] + lpos[j];
      tok_ids[slot] = t;
      tok_wt[slot] = wv[j];
    }
  }
}

// ---------------- grouped GEMM, 256x256 tile, BK=32, 4-deep ring, 32x32x16 MFMA ----------------
// PHASE 1: H[seg+m][n] = bf16(gelu(sum_k A[tok][k]*W1t[n][k] + b1[n]))   A = x_bf16 (gathered)
// PHASE 2: out[tok][n] += wt * (sum_k H[seg+m][k]*W2t[n][k] + b2[n])     A = H (direct)
template <int PHASE>
__global__ __launch_bounds__(512, 2) void moe_gemm256(
    const u16* __restrict__ A, const u16* __restrict__ Bt,
    const float* __restrict__ bias, u16* __restrict__ Hout, float* __restrict__ Out,
    const int* __restrict__ seg_off, const int* __restrict__ counts,
    const int* __restrict__ ntiles, const int* __restrict__ tile_map,
    const int* __restrict__ tok_ids, const float* __restrict__ tok_wt, int K, int N) {
  if ((int)blockIdx.x >= *ntiles) return;
  const int ent = tile_map[blockIdx.x];
  const int e = ent >> 16;
  const int mt = ent & 0xffff;
  const int cnt = counts[e];
  const int seg = seg_off[e];
  const int n0 = blockIdx.y * 256;

  const int t = threadIdx.x;          // 512
  const int w = t >> 6;               // 8 waves
  const int l = t & 63;
  const int lr = l & 31;              // row/col within 32x32 frag
  const int kb = l >> 5;              // k sub-slot (0/1)
  const int wm = w >> 2, wn = w & 3;  // 2 x 4 wave grid; wave out = 128 x 64

  // 4-deep ring: one K-tile (BK=32) per slot. A: 256x32 u16 = 16KB, B same.
  __shared__ u16 As[4][8192];
  __shared__ u16 Bs[4][8192];

  // staging source addresses. 16B unit c in [0,1024): line=c>>3 (128B lines),
  // u' = c&7, logical u = u'^(line&7), row = 2*line+(u>>2), kslot = u&3.
  const u16* aga[2];
  const u16* bga[2];
  const u16* Bte = Bt + (size_t)e * N * K;
#pragma unroll
  for (int r = 0; r < 2; ++r) {
    int c = r * 512 + t;
    int line = c >> 3;
    int u = (c & 7) ^ (line & 7);
    int row = line * 2 + (u >> 2);
    int ks = u & 3;
    int m = mt * 256 + row;
    if (m >= cnt) m = cnt - 1;
    long grow = (PHASE == 1) ? (long)tok_ids[seg + m] : (long)(seg + m);
    aga[r] = A + grow * (long)K + ks * 8;
    bga[r] = Bte + (size_t)(n0 + row) * K + ks * 8;
  }

  const int NT = K / 32;

  auto stageA = [&](int kt) {
    const int b = kt & 3;
#pragma unroll
    for (int r = 0; r < 2; ++r)
      __builtin_amdgcn_global_load_lds((gp_u32)(aga[r] + (size_t)kt * 32),
                                       (lp_u32)(&As[b][(r * 512 + w * 64) * 8]), 16, 0, 0);
  };
  auto stageB = [&](int kt) {
    const int b = kt & 3;
#pragma unroll
    for (int r = 0; r < 2; ++r)
      __builtin_amdgcn_global_load_lds((gp_u32)(bga[r] + (size_t)kt * 32),
                                       (lp_u32)(&Bs[b][(r * 512 + w * 64) * 8]), 16, 0, 0);
  };
  // read 16B frag: (row, kslot) -> swizzled LDS addr
  auto ldfrag = [&](const char* base, int row, int slot) -> bf16x8 {
    int line = row >> 1;
    int u = ((row & 1) << 2) | slot;
    int up = u ^ (line & 7);
    return *(const bf16x8*)(base + line * 128 + up * 16);
  };

  f32x16 acc[4][2];
#pragma unroll
  for (int i = 0; i < 4; ++i)
#pragma unroll
    for (int j = 0; j < 2; ++j) acc[i][j] = (f32x16)0.f;

  // prologue: stage K-tiles 0,1,2 (12 loads); tile 0 complete after vmcnt(8).
  stageA(0); stageB(0); stageA(1); stageB(1); stageA(2); stageB(2);
  asm volatile("s_waitcnt vmcnt(8)" ::: "memory");
  __builtin_amdgcn_s_barrier();

  for (int kt = 0; kt < NT; ++kt) {
    const int buf = kt & 3;
    const char* AsB = (const char*)&As[buf][0];
    const char* BsB = (const char*)&Bs[buf][0];
    bf16x8 a[2][2], b[2][2];
    // ---- phase 0: m-subtiles 0,1 ----
#pragma unroll
    for (int mi = 0; mi < 2; ++mi)
#pragma unroll
      for (int kh = 0; kh < 2; ++kh)
        a[mi][kh] = ldfrag(AsB, wm * 128 + mi * 32 + lr, kh * 2 + kb);
#pragma unroll
    for (int ni = 0; ni < 2; ++ni)
#pragma unroll
      for (int kh = 0; kh < 2; ++kh)
        b[ni][kh] = ldfrag(BsB, wn * 64 + ni * 32 + lr, kh * 2 + kb);
    if (kt + 3 < NT) stageA(kt + 3);
    __builtin_amdgcn_s_barrier();
    __builtin_amdgcn_s_setprio(1);
#pragma unroll
    for (int mi = 0; mi < 2; ++mi)
#pragma unroll
      for (int ni = 0; ni < 2; ++ni) {
        acc[mi][ni] = __builtin_amdgcn_mfma_f32_32x32x16_bf16(a[mi][0], b[ni][0], acc[mi][ni], 0, 0, 0);
        acc[mi][ni] = __builtin_amdgcn_mfma_f32_32x32x16_bf16(a[mi][1], b[ni][1], acc[mi][ni], 0, 0, 0);
      }
    __builtin_amdgcn_s_setprio(0);
    __builtin_amdgcn_s_barrier();
    // ---- phase 1: m-subtiles 2,3 (B frags reused) ----
#pragma unroll
    for (int mi = 0; mi < 2; ++mi)
#pragma unroll
      for (int kh = 0; kh < 2; ++kh)
        a[mi][kh] = ldfrag(AsB, wm * 128 + (mi + 2) * 32 + lr, kh * 2 + kb);
    if (kt + 3 < NT) {
      stageB(kt + 3);
      asm volatile("s_waitcnt vmcnt(8)" ::: "memory");
    } else if (kt + 2 < NT) {
      asm volatile("s_waitcnt vmcnt(4)" ::: "memory");
    } else if (kt + 1 < NT) {
      asm volatile("s_waitcnt vmcnt(0)" ::: "memory");
    }
    __builtin_amdgcn_s_barrier();
    __builtin_amdgcn_s_setprio(1);
#pragma unroll
    for (int mi = 0; mi < 2; ++mi)
#pragma unroll
      for (int ni = 0; ni < 2; ++ni) {
        acc[mi + 2][ni] = __builtin_amdgcn_mfma_f32_32x32x16_bf16(a[mi][0], b[ni][0], acc[mi + 2][ni], 0, 0, 0);
        acc[mi + 2][ni] = __builtin_amdgcn_mfma_f32_32x32x16_bf16(a[mi][1], b[ni][1], acc[mi + 2][ni], 0, 0, 0);
      }
    __builtin_amdgcn_s_setprio(0);
    __builtin_amdgcn_s_barrier();
  }

  // C/D layout (32x32, HW-verified): col = l&31, row = (r&3) + 8*(r>>2) + 4*(l>>5)
  const float* be = bias + (size_t)e * N;
  if (PHASE == 1) {
#pragma unroll
    for (int mi = 0; mi < 4; ++mi)
#pragma unroll
      for (int r = 0; r < 16; ++r) {
        int m = mt * 256 + wm * 128 + mi * 32 + (r & 3) + 8 * (r >> 2) + 4 * kb;
        if (m < cnt) {
          size_t hrow = (size_t)(seg + m) * N;
#pragma unroll
          for (int ni = 0; ni < 2; ++ni) {
            int col = n0 + wn * 64 + ni * 32 + lr;
            float v = acc[mi][ni][r] + be[col];
            float g = 0.5f * v * (1.0f + erff(v * 0.70710678118654752f));
            Hout[hrow + col] = f2bf(g);
          }
        }
      }
  } else {
#pragma unroll
    for (int mi = 0; mi < 4; ++mi)
#pragma unroll
      for (int r = 0; r < 16; ++r) {
        int m = mt * 256 + wm * 128 + mi * 32 + (r & 3) + 8 * (r >> 2) + 4 * kb;
        if (m < cnt) {
          int slotI = seg + m;
          int tok = tok_ids[slotI];
          float wgt = tok_wt[slotI];
          float* orow = Out + (size_t)tok * DDIM;
#pragma unroll
          for (int ni = 0; ni < 2; ++ni) {
            int col = n0 + wn * 64 + ni * 32 + lr;
            float v = (acc[mi][ni][r] + be[col]) * wgt;
            unsafeAtomicAdd(&orow[col], v);
          }
        }
      }
  }
}

// ---------------- fallback grouped GEMM (fp32 B inline-cast, 128x128) ----------------
template <int PHASE>
__global__ __launch_bounds__(256) void moe_gemm_fb(
    const u16* __restrict__ A, const float* __restrict__ Bf,
    const float* __restrict__ bias, u16* __restrict__ Hout, float* __restrict__ Out,
    const int* __restrict__ seg_off, const int* __restrict__ counts,
    const int* __restrict__ ntiles, const int* __restrict__ tile_map,
    const int* __restrict__ tok_ids, const float* __restrict__ tok_wt, int K, int N) {
  if ((int)blockIdx.x >= *ntiles) return;
  const int ent = tile_map[blockIdx.x];
  const int e = ent >> 16;
  const int mt = ent & 0xffff;
  const int cnt = counts[e];
  const int seg = seg_off[e];
  const int n0 = blockIdx.y * 128;

  const int t = threadIdx.x;
  const int w = t >> 6;
  const int l = t & 63;
  const int lr = l & 15, lh = l >> 4;
  const int wr = w >> 1, wc = w & 1;

  __shared__ u16 As[128 * 64];
  __shared__ u16 Bs[128 * 64];
  char* AsB = (char*)As;
  char* BsB = (char*)Bs;

  const u16* aga[4];
#pragma unroll
  for (int j = 0; j < 4; ++j) {
    int c = t + j * 256;
    int row = c >> 3;
    int js = (c & 7) ^ (row & 7);
    int m = mt * 128 + row;
    if (m >= cnt) m = cnt - 1;
    long grow = (PHASE == 1) ? (long)tok_ids[seg + m] : (long)(seg + m);
    aga[j] = A + grow * (long)K + js * 8;
  }
  const float* Bfe = Bf + (size_t)e * K * N;
  const int bn = t & 127;
  const int swl = bn & 7;

  f32x4 acc[4][4];
#pragma unroll
  for (int i = 0; i < 4; ++i)
#pragma unroll
    for (int j = 0; j < 4; ++j) acc[i][j] = (f32x4){0.f, 0.f, 0.f, 0.f};

  for (int kt = 0; kt < K / 64; ++kt) {
#pragma unroll
    for (int j = 0; j < 4; ++j)
      __builtin_amdgcn_global_load_lds((gp_u32)(aga[j] + kt * 64),
                                       (lp_u32)(As + (w * 64 + j * 256) * 8), 16, 0, 0);
#pragma unroll
    for (int j = 0; j < 4; ++j) {
      int kc = (t >> 7) + 2 * j;
      const float* bp = Bfe + (size_t)(kt * 64 + kc * 8) * N + (n0 + bn);
      float f[8];
#pragma unroll
      for (int i = 0; i < 8; ++i) f[i] = bp[(size_t)i * N];
      uint4 o;
      o.x = (unsigned)f2bf(f[0]) | ((unsigned)f2bf(f[1]) << 16);
      o.y = (unsigned)f2bf(f[2]) | ((unsigned)f2bf(f[3]) << 16);
      o.z = (unsigned)f2bf(f[4]) | ((unsigned)f2bf(f[5]) << 16);
      o.w = (unsigned)f2bf(f[6]) | ((unsigned)f2bf(f[7]) << 16);
      *(uint4*)(BsB + bn * 128 + ((kc ^ swl) << 4)) = o;
    }
    __syncthreads();
#pragma unroll
    for (int kk = 0; kk < 2; ++kk) {
      const int slot = kk * 4 + lh;
      bf16x8 a[4], b[4];
#pragma unroll
      for (int mi = 0; mi < 4; ++mi) {
        int row = wr * 64 + mi * 16 + lr;
        a[mi] = *(const bf16x8*)(AsB + row * 128 + ((slot ^ (row & 7)) << 4));
      }
#pragma unroll
      for (int ni = 0; ni < 4; ++ni) {
        int rowb = wc * 64 + ni * 16 + lr;
        b[ni] = *(const bf16x8*)(BsB + rowb * 128 + ((slot ^ (rowb & 7)) << 4));
      }
#pragma unroll
      for (int mi = 0; mi < 4; ++mi)
#pragma unroll
        for (int ni = 0; ni < 4; ++ni)
          acc[mi][ni] = __builtin_amdgcn_mfma_f32_16x16x32_bf16(a[mi], b[ni], acc[mi][ni], 0, 0, 0);
    }
    __syncthreads();
  }

  const float* be = bias + (size_t)e * N;
  if (PHASE == 1) {
#pragma unroll
    for (int mi = 0; mi < 4; ++mi)
#pragma unroll
      for (int r = 0; r < 4; ++r) {
        int m = mt * 128 + wr * 64 + mi * 16 + lh * 4 + r;
        if (m < cnt) {
          size_t hrow = (size_t)(seg + m) * N;
#pragma unroll
          for (int ni = 0; ni < 4; ++ni) {
            int col = n0 + wc * 64 + ni * 16 + lr;
            float v = acc[mi][ni][r] + be[col];
            float g = 0.5f * v * (1.0f + erff(v * 0.70710678118654752f));
            Hout[hrow + col] = f2bf(g);
          }
        }
      }
  } else {
#pragma unroll
    for (int mi = 0; mi < 4; ++mi)
#pragma unroll
      for (int r = 0; r < 4; ++r) {
        int m = mt * 128 + wr * 64 + mi * 16 + lh * 4 + r;
        if (m < cnt) {
          int slotI = seg + m;
          int tok = tok_ids[slotI];
          float wgt = tok_wt[slotI];
          float* orow = Out + (size_t)tok * DDIM;
#pragma unroll
          for (int ni = 0; ni < 4; ++ni) {
            int col = n0 + wc * 64 + ni * 16 + lr;
            float v = (acc[mi][ni][r] + be[col]) * wgt;
            unsafeAtomicAdd(&orow[col], v);
          }
        }
      }
  }
}

extern "C" void kernel_launch(void* const* d_in, const int* in_sizes, int n_in,
                              void* d_out, int out_size, void* d_ws, size_t ws_size,
                              hipStream_t stream) {
  const float* x  = (const float*)d_in[0];
  const float* gw = (const float*)d_in[1];
  const float* gb = (const float*)d_in[2];
  const float* w1 = (const float*)d_in[3];
  const float* b1 = (const float*)d_in[4];
  const float* w2 = (const float*)d_in[5];
  const float* b2 = (const float*)d_in[6];
  float* out = (float*)d_out;

  char* ws = (char*)d_ws;
  int*   counts  = (int*)(ws + 0);
  int*   cursors = (int*)(ws + 64);
  int*   seg     = (int*)(ws + 128);
  int*   nt256   = (int*)(ws + 192);
  int*   map256  = (int*)(ws + 256);
  int*   nt128   = (int*)(ws + 1024);
  int*   map128  = (int*)(ws + 2048);
  int*   top_e   = (int*)(ws + 4096);
  float* top_w   = (float*)(ws + 4096 + 65536);
  int*   tok_ids = (int*)(ws + 4096 + 131072);
  float* tok_wt  = (float*)(ws + 4096 + 196608);
  u16*   x_bf    = (u16*)(ws + ((size_t)1 << 20));    //  16 MB
  u16*   H       = (u16*)(ws + ((size_t)17 << 20));   // 128 MB
  u16*   wt      = (u16*)(ws + ((size_t)145 << 20));  //  64 MB (shared w1t/w2t)

  const bool pre = ws_size >= ((size_t)209 << 20);

  hipMemsetAsync(ws, 0, 256, stream);
  hipMemsetAsync(d_out, 0, (size_t)out_size * sizeof(float), stream);

  cast_x_kernel<<<TK * DDIM / 8 / 256, 256, 0, stream>>>((const float4*)x, (uint4*)x_bf);
  router_kernel<<<TK, 64, 0, stream>>>(x, gw, gb, top_e, top_w);
  count_kernel<<<TK / 256, 256, 0, stream>>>(top_e, counts);
  scan_kernel<<<1, 64, 0, stream>>>(counts, seg, cursors, nt256, map256, nt128, map128);
  scatter_kernel<<<TK / 256, 256, 0, stream>>>(top_e, top_w, cursors, tok_ids, tok_wt);

  if (pre) {
    transpose_cast_kernel<<<dim3(DDIM / 64, FDIM / 64, NEXP), 256, 0, stream>>>(w1, wt, DDIM, FDIM);
    moe_gemm256<1><<<dim3(MAXT256, FDIM / 256), 512, 0, stream>>>(
        x_bf, wt, b1, H, nullptr, seg, counts, nt256, map256, tok_ids, tok_wt, DDIM, FDIM);
    transpose_cast_kernel<<<dim3(FDIM / 64, DDIM / 64, NEXP), 256, 0, stream>>>(w2, wt, FDIM, DDIM);
    moe_gemm256<2><<<dim3(MAXT256, DDIM / 256), 512, 0, stream>>>(
        H, wt, b2, nullptr, out, seg, counts, nt256, map256, tok_ids, tok_wt, FDIM, DDIM);
  } else {
    moe_gemm_fb<1><<<dim3(MAXT128, FDIM / 128), 256, 0, stream>>>(
        x_bf, w1, b1, H, nullptr, seg, counts, nt128, map128, tok_ids, tok_wt, DDIM, FDIM);
    moe_gemm_fb<2><<<dim3(MAXT128, DDIM / 128), 256, 0, stream>>>(
        H, w2, b2, nullptr, out, seg, counts, nt128, map128, tok_ids, tok_wt, FDIM, DDIM);
  }
}

// Round 5
// 709.971 us; speedup vs baseline: 1.1635x; 1.1635x over previous
//
#include <hip/hip_runtime.h>
#include <hip/hip_bf16.h>
#include <math.h>

// MoE: T=8192 tokens, D=1024, E=8 experts, F=4096, top-2 routing.
// Pipeline: cast -> router -> count -> scan(tile map) -> scatter(+inverse map)
//   -> transpose(w1) -> GEMM1(gelu)->H -> transpose(w2) -> GEMM2(plain)->Y -> combine.
// GEMM: 128x128 tile, BK=64, 4 waves, 16x16x32 MFMA, XOR-swizzled LDS (0-conflict
// verified in R2), double-buffered with counted vmcnt(8), global_load_lds staging.
// Grid: 1D, n-fastest within m-tile, bijective XCD swizzle (m204) so each XCD's
// consecutive work shares one A-panel in its private L2.

#define TK 8192
#define DDIM 1024
#define FDIM 4096
#define NEXP 8
#define MAXT128 136

typedef unsigned short u16;
typedef __attribute__((ext_vector_type(8))) short bf16x8;
typedef __attribute__((ext_vector_type(4))) float f32x4;

typedef const __attribute__((address_space(1))) unsigned int* gp_u32;
typedef __attribute__((address_space(3))) unsigned int* lp_u32;

__device__ __forceinline__ u16 f2bf(float f) {
  unsigned x = __float_as_uint(f);
  x += 0x7fffu + ((x >> 16) & 1u);
  return (u16)(x >> 16);
}

// ---------------- cast x (fp32 -> bf16), 8 elems/thread ----------------
__global__ void cast_x_kernel(const float4* __restrict__ x, uint4* __restrict__ xb) {
  int i = blockIdx.x * blockDim.x + threadIdx.x;
  float4 a = x[2 * i], b = x[2 * i + 1];
  uint4 o;
  o.x = (unsigned)f2bf(a.x) | ((unsigned)f2bf(a.y) << 16);
  o.y = (unsigned)f2bf(a.z) | ((unsigned)f2bf(a.w) << 16);
  o.z = (unsigned)f2bf(b.x) | ((unsigned)f2bf(b.y) << 16);
  o.w = (unsigned)f2bf(b.z) | ((unsigned)f2bf(b.w) << 16);
  xb[i] = o;
}

// ---------------- weight transpose + cast: [E][K][N] f32 -> [E][N][K] bf16 ----------------
__global__ void transpose_cast_kernel(const float* __restrict__ src, u16* __restrict__ dst,
                                      int K, int N) {
  __shared__ float tile[64][65];
  const int t = threadIdx.x;
  const float* s = src + (size_t)blockIdx.z * K * N + (size_t)(blockIdx.x * 64) * N + blockIdx.y * 64;
  u16* d = dst + (size_t)blockIdx.z * N * K + (size_t)(blockIdx.y * 64) * K + blockIdx.x * 64;
#pragma unroll
  for (int r = 0; r < 16; ++r) {
    int idx = r * 256 + t;
    int kk = idx >> 6, nn = idx & 63;
    tile[kk][nn] = s[(size_t)kk * N + nn];
  }
  __syncthreads();
#pragma unroll
  for (int r = 0; r < 16; ++r) {
    int idx = r * 256 + t;
    int nn = idx >> 6, kk = idx & 63;
    d[(size_t)nn * K + kk] = f2bf(tile[kk][nn]);
  }
}

// ---------------- router: one wave per token ----------------
__global__ void router_kernel(const float* __restrict__ x, const float* __restrict__ gw,
                              const float* __restrict__ gb,
                              int* __restrict__ top_e, float* __restrict__ top_w) {
  const int t = blockIdx.x;
  const int l = threadIdx.x;  // 64
  const float* xr = x + (size_t)t * DDIM;
  float acc[8] = {0, 0, 0, 0, 0, 0, 0, 0};
  for (int k = l; k < DDIM; k += 64) {
    float xv = xr[k];
    const float4* g4 = (const float4*)(gw + (size_t)k * 8);
    float4 ga = g4[0], gbv = g4[1];
    acc[0] = fmaf(xv, ga.x, acc[0]);  acc[1] = fmaf(xv, ga.y, acc[1]);
    acc[2] = fmaf(xv, ga.z, acc[2]);  acc[3] = fmaf(xv, ga.w, acc[3]);
    acc[4] = fmaf(xv, gbv.x, acc[4]); acc[5] = fmaf(xv, gbv.y, acc[5]);
    acc[6] = fmaf(xv, gbv.z, acc[6]); acc[7] = fmaf(xv, gbv.w, acc[7]);
  }
#pragma unroll
  for (int e = 0; e < 8; ++e)
#pragma unroll
    for (int m = 32; m; m >>= 1) acc[e] += __shfl_xor(acc[e], m, 64);
  if (l == 0) {
    float lg[8];
#pragma unroll
    for (int e = 0; e < 8; ++e) lg[e] = acc[e] + gb[e];
    int i1 = 0;
#pragma unroll
    for (int e = 1; e < 8; ++e) if (lg[e] > lg[i1]) i1 = e;
    int i2 = (i1 == 0) ? 1 : 0;
#pragma unroll
    for (int e = 0; e < 8; ++e) if (e != i1 && lg[e] > lg[i2]) i2 = e;
    float e2 = __expf(lg[i2] - lg[i1]);
    float inv = 1.0f / (1.0f + e2);
    top_e[2 * t] = i1;      top_e[2 * t + 1] = i2;
    top_w[2 * t] = inv;     top_w[2 * t + 1] = e2 * inv;
  }
}

// ---------------- count ----------------
__global__ void count_kernel(const int* __restrict__ top_e, int* __restrict__ counts) {
  __shared__ int lc[8];
  if (threadIdx.x < 8) lc[threadIdx.x] = 0;
  __syncthreads();
  int t = blockIdx.x * 256 + threadIdx.x;
  if (t < TK) {
    atomicAdd(&lc[top_e[2 * t]], 1);
    atomicAdd(&lc[top_e[2 * t + 1]], 1);
  }
  __syncthreads();
  if (threadIdx.x < 8) atomicAdd(&counts[threadIdx.x], lc[threadIdx.x]);
}

// ---------------- scan + tile map (128-row granularity) ----------------
__global__ void scan_kernel(const int* __restrict__ counts, int* __restrict__ seg,
                            int* __restrict__ cur, int* __restrict__ nt128,
                            int* __restrict__ map128) {
  if (threadIdx.x == 0) {
    int s = 0, i128 = 0;
    for (int e = 0; e < 8; ++e) {
      seg[e] = s; cur[e] = s;
      int c = counts[e];
      for (int mt = 0; mt * 128 < c; ++mt) map128[i128++] = (e << 16) | mt;
      s += c;
    }
    seg[8] = s;
    *nt128 = i128;
  }
}

// ---------------- scatter (+ inverse map for combine) ----------------
__global__ void scatter_kernel(const int* __restrict__ top_e, const float* __restrict__ top_w,
                               int* __restrict__ cur, int* __restrict__ tok_ids,
                               float* __restrict__ tok_wt, int* __restrict__ inv) {
  __shared__ int lcnt[8];
  __shared__ int lbase[8];
  if (threadIdx.x < 8) lcnt[threadIdx.x] = 0;
  __syncthreads();
  int t = blockIdx.x * 256 + threadIdx.x;
  int e[2]; float wv[2]; int lpos[2];
  bool valid = t < TK;
  if (valid) {
#pragma unroll
    for (int j = 0; j < 2; ++j) {
      e[j] = top_e[2 * t + j];
      wv[j] = top_w[2 * t + j];
      lpos[j] = atomicAdd(&lcnt[e[j]], 1);
    }
  }
  __syncthreads();
  if (threadIdx.x < 8) lbase[threadIdx.x] = atomicAdd(&cur[threadIdx.x], lcnt[threadIdx.x]);
  __syncthreads();
  if (valid) {
#pragma unroll
    for (int j = 0; j < 2; ++j) {
      int slot = lbase[e[j]] + lpos[j];
      tok_ids[slot] = t;
      tok_wt[slot] = wv[j];
      inv[2 * t + j] = slot;
    }
  }
}

// ---------------- grouped GEMM, 128x128, BK=64, double-buffered, counted vmcnt ----------------
// PHASE 1: H[seg+m][n] = bf16(gelu(acc + b1[n]))        A = x_bf16 (gathered via tok_ids)
// PHASE 2: out[tok][n] += wt * (acc + b2[n])  (atomic fallback)
// PHASE 3: Y[seg+m][n] = bf16(acc + b2[n])    (plain store; combined later)
template <int PHASE>
__global__ __launch_bounds__(256) void moe_gemm_db(
    const u16* __restrict__ A, const u16* __restrict__ Bt,
    const float* __restrict__ bias, u16* __restrict__ Hout, float* __restrict__ Out,
    u16* __restrict__ Yout,
    const int* __restrict__ seg_off, const int* __restrict__ counts,
    const int* __restrict__ ntiles, const int* __restrict__ tile_map,
    const int* __restrict__ tok_ids, const float* __restrict__ tok_wt,
    int K, int N, int lognb) {
  // 1D grid: work = mtIdx * NB + nIdx (n fastest). Bijective XCD swizzle (m204):
  // xcd = bid&7 owns a contiguous chunk of work-space -> A-panel reuse in XCD L2.
  const int nb = 1 << lognb;
  const int nwg = (*ntiles) << lognb;
  const int bid = (int)blockIdx.x;
  if (bid >= nwg) return;
  const int q = nwg >> 3, rr = nwg & 7;
  const int xcd = bid & 7, pos = bid >> 3;
  const int work = xcd * q + (xcd < rr ? xcd : rr) + pos;
  const int mtIdx = work >> lognb;
  const int n0 = (work & (nb - 1)) * 128;

  const int ent = tile_map[mtIdx];
  const int e = ent >> 16;
  const int mt = ent & 0xffff;
  const int cnt = counts[e];
  const int seg = seg_off[e];

  const int t = threadIdx.x;
  const int w = t >> 6;
  const int l = t & 63;
  const int lr = l & 15, lh = l >> 4;
  const int wr = w >> 1, wc = w & 1;

  __shared__ u16 As[2][128 * 64];
  __shared__ u16 Bs[2][128 * 64];

  // staging descriptors: chunk c = t + 256j; row=c>>3, swizzled k-slot js=(c&7)^(row&7)
  const u16* aga[4];
  const u16* bga[4];
  const u16* Bte = Bt + (size_t)e * N * K;
#pragma unroll
  for (int j = 0; j < 4; ++j) {
    int c = t + j * 256;
    int row = c >> 3;
    int js = (c & 7) ^ (row & 7);
    int m = mt * 128 + row;
    if (m >= cnt) m = cnt - 1;
    long grow = (PHASE == 1) ? (long)tok_ids[seg + m] : (long)(seg + m);
    aga[j] = A + grow * (long)K + js * 8;
    bga[j] = Bte + (size_t)(n0 + row) * K + js * 8;
  }

  const int NT = K / 64;

  auto STAGE = [&](int buf, int kt) {
#pragma unroll
    for (int j = 0; j < 4; ++j)
      __builtin_amdgcn_global_load_lds((gp_u32)(aga[j] + (size_t)kt * 64),
                                       (lp_u32)(&As[buf][0] + (w * 64 + j * 256) * 8), 16, 0, 0);
#pragma unroll
    for (int j = 0; j < 4; ++j)
      __builtin_amdgcn_global_load_lds((gp_u32)(bga[j] + (size_t)kt * 64),
                                       (lp_u32)(&Bs[buf][0] + (w * 64 + j * 256) * 8), 16, 0, 0);
  };

  f32x4 acc[4][4];
#pragma unroll
  for (int i = 0; i < 4; ++i)
#pragma unroll
    for (int j = 0; j < 4; ++j) acc[i][j] = (f32x4){0.f, 0.f, 0.f, 0.f};

  STAGE(0, 0);

  for (int kt = 0; kt < NT; ++kt) {
    const int cur = kt & 1;
    if (kt + 1 < NT) {
      STAGE(cur ^ 1, kt + 1);
      asm volatile("s_waitcnt vmcnt(8)" ::: "memory");
    } else {
      asm volatile("s_waitcnt vmcnt(0)" ::: "memory");
    }
    __builtin_amdgcn_s_barrier();

    const char* AsB = (const char*)&As[cur][0];
    const char* BsB = (const char*)&Bs[cur][0];
#pragma unroll
    for (int kk = 0; kk < 2; ++kk) {
      const int slot = kk * 4 + lh;
      bf16x8 a[4], b[4];
#pragma unroll
      for (int mi = 0; mi < 4; ++mi) {
        int row = wr * 64 + mi * 16 + lr;
        a[mi] = *(const bf16x8*)(AsB + row * 128 + ((slot ^ (row & 7)) << 4));
      }
#pragma unroll
      for (int ni = 0; ni < 4; ++ni) {
        int rowb = wc * 64 + ni * 16 + lr;
        b[ni] = *(const bf16x8*)(BsB + rowb * 128 + ((slot ^ (rowb & 7)) << 4));
      }
#pragma unroll
      for (int mi = 0; mi < 4; ++mi)
#pragma unroll
        for (int ni = 0; ni < 4; ++ni)
          acc[mi][ni] = __builtin_amdgcn_mfma_f32_16x16x32_bf16(a[mi], b[ni], acc[mi][ni], 0, 0, 0);
    }
    asm volatile("s_waitcnt lgkmcnt(0)" ::: "memory");
    __builtin_amdgcn_s_barrier();
  }

  const float* be = bias + (size_t)e * N;
#pragma unroll
  for (int mi = 0; mi < 4; ++mi)
#pragma unroll
    for (int r = 0; r < 4; ++r) {
      int m = mt * 128 + wr * 64 + mi * 16 + lh * 4 + r;
      if (m < cnt) {
        if (PHASE == 1) {
          size_t hrow = (size_t)(seg + m) * N;
#pragma unroll
          for (int ni = 0; ni < 4; ++ni) {
            int col = n0 + wc * 64 + ni * 16 + lr;
            float v = acc[mi][ni][r] + be[col];
            float g = 0.5f * v * (1.0f + erff(v * 0.70710678118654752f));
            Hout[hrow + col] = f2bf(g);
          }
        } else if (PHASE == 3) {
          size_t yrow = (size_t)(seg + m) * N;
#pragma unroll
          for (int ni = 0; ni < 4; ++ni) {
            int col = n0 + wc * 64 + ni * 16 + lr;
            Yout[yrow + col] = f2bf(acc[mi][ni][r] + be[col]);
          }
        } else {
          int slotI = seg + m;
          int tok = tok_ids[slotI];
          float wgt = tok_wt[slotI];
          float* orow = Out + (size_t)tok * DDIM;
#pragma unroll
          for (int ni = 0; ni < 4; ++ni) {
            int col = n0 + wc * 64 + ni * 16 + lr;
            unsafeAtomicAdd(&orow[col], (acc[mi][ni][r] + be[col]) * wgt);
          }
        }
      }
    }
}

// ---------------- combine: out[t] = w0*Y[inv0] + w1*Y[inv1] ----------------
__global__ void combine_kernel(const u16* __restrict__ Y, const int* __restrict__ inv,
                               const float* __restrict__ top_w, float* __restrict__ out) {
  int idx = blockIdx.x * 256 + threadIdx.x;   // TK*128 threads, 8 cols each
  int t = idx >> 7, c = (idx & 127) * 8;
  int s0 = inv[2 * t], s1 = inv[2 * t + 1];
  float w0 = top_w[2 * t], w1 = top_w[2 * t + 1];
  const uint4 y0 = *(const uint4*)(Y + (size_t)s0 * DDIM + c);
  const uint4 y1 = *(const uint4*)(Y + (size_t)s1 * DDIM + c);
  float4 o0, o1;
#define LO(u) __uint_as_float((u) << 16)
#define HI(u) __uint_as_float((u) & 0xffff0000u)
  o0.x = w0 * LO(y0.x) + w1 * LO(y1.x); o0.y = w0 * HI(y0.x) + w1 * HI(y1.x);
  o0.z = w0 * LO(y0.y) + w1 * LO(y1.y); o0.w = w0 * HI(y0.y) + w1 * HI(y1.y);
  o1.x = w0 * LO(y0.z) + w1 * LO(y1.z); o1.y = w0 * HI(y0.z) + w1 * HI(y1.z);
  o1.z = w0 * LO(y0.w) + w1 * LO(y1.w); o1.w = w0 * HI(y0.w) + w1 * HI(y1.w);
#undef LO
#undef HI
  float4* op = (float4*)(out + (size_t)t * DDIM + c);
  op[0] = o0; op[1] = o1;
}

extern "C" void kernel_launch(void* const* d_in, const int* in_sizes, int n_in,
                              void* d_out, int out_size, void* d_ws, size_t ws_size,
                              hipStream_t stream) {
  const float* x  = (const float*)d_in[0];
  const float* gw = (const float*)d_in[1];
  const float* gb = (const float*)d_in[2];
  const float* w1 = (const float*)d_in[3];
  const float* b1 = (const float*)d_in[4];
  const float* w2 = (const float*)d_in[5];
  const float* b2 = (const float*)d_in[6];
  float* out = (float*)d_out;

  char* ws = (char*)d_ws;
  int*   counts  = (int*)(ws + 0);
  int*   cursors = (int*)(ws + 64);
  int*   seg     = (int*)(ws + 128);
  int*   nt128   = (int*)(ws + 1024);
  int*   map128  = (int*)(ws + 2048);
  int*   top_e   = (int*)(ws + 4096);
  float* top_w   = (float*)(ws + 4096 + 65536);
  int*   tok_ids = (int*)(ws + 4096 + 131072);
  float* tok_wt  = (float*)(ws + 4096 + 196608);
  int*   invm    = (int*)(ws + 4096 + 262144);
  u16*   x_bf    = (u16*)(ws + ((size_t)1 << 20));    //  16 MB
  u16*   H       = (u16*)(ws + ((size_t)17 << 20));   // 128 MB
  u16*   wt      = (u16*)(ws + ((size_t)145 << 20));  //  64 MB (shared w1t/w2t)
  u16*   Y       = (u16*)(ws + ((size_t)209 << 20));  //  33.6 MB (bf16 per-slot rows)

  const bool useY = ws_size >= ((size_t)243 << 20);

  hipMemsetAsync(ws, 0, 256, stream);

  cast_x_kernel<<<TK * DDIM / 8 / 256, 256, 0, stream>>>((const float4*)x, (uint4*)x_bf);
  router_kernel<<<TK, 64, 0, stream>>>(x, gw, gb, top_e, top_w);
  count_kernel<<<TK / 256, 256, 0, stream>>>(top_e, counts);
  scan_kernel<<<1, 64, 0, stream>>>(counts, seg, cursors, nt128, map128);
  scatter_kernel<<<TK / 256, 256, 0, stream>>>(top_e, top_w, cursors, tok_ids, tok_wt, invm);

  transpose_cast_kernel<<<dim3(DDIM / 64, FDIM / 64, NEXP), 256, 0, stream>>>(w1, wt, DDIM, FDIM);
  moe_gemm_db<1><<<dim3(MAXT128 * (FDIM / 128)), 256, 0, stream>>>(
      x_bf, wt, b1, H, nullptr, nullptr, seg, counts, nt128, map128, tok_ids, tok_wt,
      DDIM, FDIM, 5);
  transpose_cast_kernel<<<dim3(FDIM / 64, DDIM / 64, NEXP), 256, 0, stream>>>(w2, wt, FDIM, DDIM);

  if (useY) {
    moe_gemm_db<3><<<dim3(MAXT128 * (DDIM / 128)), 256, 0, stream>>>(
        H, wt, b2, nullptr, nullptr, Y, seg, counts, nt128, map128, tok_ids, tok_wt,
        FDIM, DDIM, 3);
    combine_kernel<<<TK * 128 / 256, 256, 0, stream>>>(Y, invm, top_w, out);
  } else {
    hipMemsetAsync(d_out, 0, (size_t)out_size * sizeof(float), stream);
    moe_gemm_db<2><<<dim3(MAXT128 * (DDIM / 128)), 256, 0, stream>>>(
        H, wt, b2, nullptr, out, nullptr, seg, counts, nt128, map128, tok_ids, tok_wt,
        FDIM, DDIM, 3);
  }
}